// Round 4
// baseline (56.388 us; speedup 1.0000x reference)
//
#include <hip/hip_runtime.h>

#define DIN  128
#define DOUT 32

// ---------------- Kernel 1: HW = H @ W  (fp32 vector ALU) -------------------
// 256 threads/block, 256 rows/block. Thread = (rg 0..31, cg 0..7) computes
// 8 consecutive rows x 4 cols. H read from global with distance-1 register
// prefetch (all loads base+imm off one pointer); W (16 KB) in LDS [k][cg],
// conflict-free. Last block clamps its row base -> duplicate identical work,
// no guards in the hot loop. Requires n >= 256 (launcher falls back otherwise).
__global__ __launch_bounds__(256) void gemm_hw_kernel(
    const float* __restrict__ H, const float* __restrict__ W,
    float* __restrict__ HW, int n)
{
    __shared__ float4 W4lds[DIN * (DOUT / 4)];   // [k][cg], 16 KB
    const int tid = threadIdx.x;

    #pragma unroll
    for (int i = tid; i < DIN * (DOUT / 4); i += 256)
        W4lds[i] = reinterpret_cast<const float4*>(W)[i];
    __syncthreads();

    const int rg = tid >> 3;      // 0..31
    const int cg = tid & 7;       // 0..7
    int r0 = blockIdx.x * 256 + rg * 8;
    if (r0 + 8 > n) r0 = n - 8;   // overlap-recompute at the tail (identical values)

    // 8 consecutive rows: H4[(r0+i)*32 + k4] = hp[i*32 + k4], all base+imm.
    const float4* __restrict__ hp =
        reinterpret_cast<const float4*>(H) + (size_t)r0 * (DIN / 4);

    float4 acc0 = {0,0,0,0}, acc1 = {0,0,0,0}, acc2 = {0,0,0,0}, acc3 = {0,0,0,0};
    float4 acc4 = {0,0,0,0}, acc5 = {0,0,0,0}, acc6 = {0,0,0,0}, acc7 = {0,0,0,0};

    // Current k4-slice of the 8 rows.
    float4 c0 = hp[0*32], c1 = hp[1*32], c2 = hp[2*32], c3 = hp[3*32];
    float4 c4 = hp[4*32], c5 = hp[5*32], c6 = hp[6*32], c7 = hp[7*32];

    #pragma unroll 2
    for (int k4 = 0; k4 < DIN / 4; ++k4) {
        const int kn = (k4 + 1) & (DIN / 4 - 1);   // wraps at end: harmless reload
        // Prefetch next k4-slice (overlaps the FMA block below).
        const float4 n0 = hp[0*32 + kn], n1 = hp[1*32 + kn];
        const float4 n2 = hp[2*32 + kn], n3 = hp[3*32 + kn];
        const float4 n4 = hp[4*32 + kn], n5 = hp[5*32 + kn];
        const float4 n6 = hp[6*32 + kn], n7 = hp[7*32 + kn];

        const float4 w0 = W4lds[(k4 * 4 + 0) * 8 + cg];
        const float4 w1 = W4lds[(k4 * 4 + 1) * 8 + cg];
        const float4 w2 = W4lds[(k4 * 4 + 2) * 8 + cg];
        const float4 w3 = W4lds[(k4 * 4 + 3) * 8 + cg];

        #define FMA4(A, S, WV)                      \
            A.x = fmaf(S, WV.x, A.x);               \
            A.y = fmaf(S, WV.y, A.y);               \
            A.z = fmaf(S, WV.z, A.z);               \
            A.w = fmaf(S, WV.w, A.w);
        #define ROW(A, HV) FMA4(A, HV.x, w0) FMA4(A, HV.y, w1) FMA4(A, HV.z, w2) FMA4(A, HV.w, w3)
        ROW(acc0, c0) ROW(acc1, c1) ROW(acc2, c2) ROW(acc3, c3)
        ROW(acc4, c4) ROW(acc5, c5) ROW(acc6, c6) ROW(acc7, c7)
        #undef ROW
        #undef FMA4

        c0 = n0; c1 = n1; c2 = n2; c3 = n3;
        c4 = n4; c5 = n5; c6 = n6; c7 = n7;
    }

    float4* __restrict__ hw4 =
        reinterpret_cast<float4*>(HW) + (size_t)r0 * (DOUT / 4) + cg;
    hw4[0*8] = acc0; hw4[1*8] = acc1; hw4[2*8] = acc2; hw4[3*8] = acc3;
    hw4[4*8] = acc4; hw4[5*8] = acc5; hw4[6*8] = acc6; hw4[7*8] = acc7;
}

// ---------------- Kernel 2: out = A_csr @ HW  (SpMM, float4 + deep unroll) --
__global__ __launch_bounds__(256) void spmm_kernel(
    const float* __restrict__ HWf, const int* __restrict__ rowPtr,
    const int* __restrict__ colIdx, const float* __restrict__ val,
    float* __restrict__ out, int n)
{
    const float4* HW4 = reinterpret_cast<const float4*>(HWf);
    const int gid = blockIdx.x * 256 + threadIdx.x;
    const int row = gid >> 3;
    if (row >= n) return;
    const int cg = gid & 7;

    const int start = rowPtr[row];
    const int end   = rowPtr[row + 1];
    float4 acc = {0.f, 0.f, 0.f, 0.f};

    #define GATHER_FMA(E)                                                    \
        { const int   c_ = colIdx[E];                                        \
          const float v_ = val[E];                                           \
          const float4 h_ = HW4[(size_t)c_ * (DOUT / 4) + cg];               \
          acc.x = fmaf(v_, h_.x, acc.x);                                     \
          acc.y = fmaf(v_, h_.y, acc.y);                                     \
          acc.z = fmaf(v_, h_.z, acc.z);                                     \
          acc.w = fmaf(v_, h_.w, acc.w); }

    int e = start;
    for (; e + 8 <= end; e += 8) {
        GATHER_FMA(e + 0) GATHER_FMA(e + 1) GATHER_FMA(e + 2) GATHER_FMA(e + 3)
        GATHER_FMA(e + 4) GATHER_FMA(e + 5) GATHER_FMA(e + 6) GATHER_FMA(e + 7)
    }
    for (; e + 4 <= end; e += 4) {
        GATHER_FMA(e + 0) GATHER_FMA(e + 1) GATHER_FMA(e + 2) GATHER_FMA(e + 3)
    }
    for (; e < end; ++e) { GATHER_FMA(e) }
    #undef GATHER_FMA

    reinterpret_cast<float4*>(out)[(size_t)row * (DOUT / 4) + cg] = acc;
}

// ---------------- Fallback: fused (ws too small or tiny n) ------------------
__global__ __launch_bounds__(256) void fused_kernel(
    const float* __restrict__ H, const float* __restrict__ W,
    const int* __restrict__ rowPtr, const int* __restrict__ colIdx,
    const float* __restrict__ val, float* __restrict__ out, int n)
{
    __shared__ float Wlds[DIN * DOUT];
    for (int i = threadIdx.x; i < DIN * DOUT; i += 256) Wlds[i] = W[i];
    __syncthreads();

    const int gid = blockIdx.x * 256 + threadIdx.x;
    const int row = gid >> 5;
    if (row >= n) return;
    const int c = gid & 31;

    const int start = rowPtr[row];
    const int end   = rowPtr[row + 1];
    float acc = 0.f;
    for (int e = start; e < end; ++e) {
        const int   cidx = colIdx[e];
        const float v    = val[e];
        const float* h = H + (size_t)cidx * DIN;
        float dot = 0.f;
        #pragma unroll 8
        for (int k = 0; k < DIN; ++k)
            dot = fmaf(h[k], Wlds[k * DOUT + c], dot);
        acc = fmaf(v, dot, acc);
    }
    out[(size_t)row * DOUT + c] = acc;
}

extern "C" void kernel_launch(void* const* d_in, const int* in_sizes, int n_in,
                              void* d_out, int out_size, void* d_ws, size_t ws_size,
                              hipStream_t stream)
{
    const float* H      = (const float*)d_in[0];
    const float* W      = (const float*)d_in[1];
    const int*   rowPtr = (const int*)d_in[2];
    const int*   colIdx = (const int*)d_in[3];
    const float* val    = (const float*)d_in[4];
    float*       out    = (float*)d_out;

    const int n = in_sizes[2] - 1;           // rowPtr has N+1 entries
    const size_t hw_bytes = (size_t)n * DOUT * sizeof(float);

    if (ws_size >= hw_bytes && n >= 256) {
        float* HW = (float*)d_ws;
        gemm_hw_kernel<<<(n + 255) / 256, 256, 0, stream>>>(H, W, HW, n);
        const int spmm_blocks = (int)(((size_t)n * (DOUT / 4) + 255) / 256);
        spmm_kernel<<<spmm_blocks, 256, 0, stream>>>(HW, rowPtr, colIdx, val, out, n);
    } else {
        const int blocks = (int)(((size_t)n * DOUT + 255) / 256);
        fused_kernel<<<blocks, 256, 0, stream>>>(H, W, rowPtr, colIdx, val, out, n);
    }
}

// Round 5
// 54.001 us; speedup vs baseline: 1.0442x; 1.0442x over previous
//
#include <hip/hip_runtime.h>

#define DIN  128
#define DOUT 32
#define GBM  128   // rows per GEMM block

// f32 -> bf16, round-to-nearest-even
__device__ __forceinline__ unsigned int f2b(float f) {
    unsigned int u = __float_as_uint(f);
    return (u + 0x7fffu + ((u >> 16) & 1u)) >> 16;
}
__device__ __forceinline__ unsigned int pack2(float lo, float hi) {
    return f2b(lo) | (f2b(hi) << 16);
}

// ---------------- Kernel 1: HWb = bf16(H @ W) -------------------------------
// 256 threads/block = 2 k-halves x 128 rows. Thread computes 1 row x 32 cols
// over 64 k-values: per k4-iter {1 global b128 (unique! no cg duplication),
// 32 wave-uniform LDS broadcast reads, 128 FMA}. Distance-1 prefetch covers
// the single load. Partials merged via padded LDS, stores fully coalesced.
__global__ __launch_bounds__(256) void gemm_hw_kernel(
    const float* __restrict__ H, const float* __restrict__ W,
    unsigned short* __restrict__ HWb, int n)
{
    __shared__ float4 W4[DIN * (DOUT / 4)];   // [k*8 + c4], 16 KB
    __shared__ float4 red[GBM * 9];           // [lrow*9 + c4], padded, 18 KB
    const int tid = threadIdx.x;

    #pragma unroll
    for (int i = tid; i < DIN * (DOUT / 4); i += 256)
        W4[i] = reinterpret_cast<const float4*>(W)[i];
    __syncthreads();

    const int kh   = tid >> 7;     // 0..1
    const int lrow = tid & 127;
    int row = blockIdx.x * GBM + lrow;
    if (row >= n) row = n - 1;     // tail: duplicate compute, stores guarded

    const float4* __restrict__ hp =
        reinterpret_cast<const float4*>(H) + (size_t)row * (DIN / 4) + kh * 16;

    float4 acc[8];
    #pragma unroll
    for (int c = 0; c < 8; ++c) acc[c] = make_float4(0.f, 0.f, 0.f, 0.f);

    float4 cur = hp[0];
    #pragma unroll 4
    for (int i = 0; i < 16; ++i) {
        const float4 nxt = hp[(i + 1) & 15];      // wrap reload: harmless
        const int k4 = (kh << 4) + i;
        #pragma unroll
        for (int ks = 0; ks < 4; ++ks) {
            const float s = (ks == 0) ? cur.x : (ks == 1) ? cur.y
                          : (ks == 2) ? cur.z : cur.w;
            #pragma unroll
            for (int c = 0; c < 8; ++c) {
                const float4 w = W4[(k4 * 4 + ks) * 8 + c];
                acc[c].x = fmaf(s, w.x, acc[c].x);
                acc[c].y = fmaf(s, w.y, acc[c].y);
                acc[c].z = fmaf(s, w.z, acc[c].z);
                acc[c].w = fmaf(s, w.w, acc[c].w);
            }
        }
        cur = nxt;
    }

    // Merge the two k-halves.
    if (kh == 1) {
        #pragma unroll
        for (int c = 0; c < 8; ++c) red[lrow * 9 + c] = acc[c];
    }
    __syncthreads();
    if (kh == 0) {
        #pragma unroll
        for (int c = 0; c < 8; ++c) {
            float4 r = red[lrow * 9 + c];
            r.x += acc[c].x; r.y += acc[c].y;
            r.z += acc[c].z; r.w += acc[c].w;
            red[lrow * 9 + c] = r;
        }
    }
    __syncthreads();

    // Coalesced bf16 store: 128 rows x 32 bf16 = 512 x 16B chunks.
    const int base = blockIdx.x * GBM;
    uint4* __restrict__ o16 = reinterpret_cast<uint4*>(HWb);
    #pragma unroll
    for (int j = 0; j < 2; ++j) {
        const int flat = j * 256 + tid;   // 0..511
        const int r    = flat >> 2;       // 0..127
        const int cc   = flat & 3;        // chunk of 8 bf16
        if (base + r < n) {
            const float4 a = red[r * 9 + cc * 2];
            const float4 b = red[r * 9 + cc * 2 + 1];
            uint4 p;
            p.x = pack2(a.x, a.y); p.y = pack2(a.z, a.w);
            p.z = pack2(b.x, b.y); p.w = pack2(b.z, b.w);
            o16[(size_t)(base + r) * 4 + cc] = p;
        }
    }
}

// ---------------- Kernel 2: out = A_csr @ HWb  (bf16 gather SpMM) -----------
// 4 threads/row, 8 cols each: 16B gather per edge (half the bytes of f32;
// 6.4 MB table is per-XCD-L2-resident). 8-edge unroll keeps 8 gathers in
// flight. Accumulation order matches the reference (ascending e).
__global__ __launch_bounds__(256) void spmm_kernel(
    const unsigned short* __restrict__ HWb, const int* __restrict__ rowPtr,
    const int* __restrict__ colIdx, const float* __restrict__ val,
    float* __restrict__ out, int n)
{
    const uint4* __restrict__ tbl = reinterpret_cast<const uint4*>(HWb);
    const int gid = blockIdx.x * 256 + threadIdx.x;
    const int row = gid >> 2;
    if (row >= n) return;
    const int cg = gid & 3;

    const int start = rowPtr[row];
    const int end   = rowPtr[row + 1];
    float a0=0,a1=0,a2=0,a3=0,a4=0,a5=0,a6=0,a7=0;

    #define BLO(u) __uint_as_float((u) << 16)
    #define BHI(u) __uint_as_float((u) & 0xffff0000u)
    #define STEP(E) {                                                        \
        const int   c_ = colIdx[E];                                          \
        const float v_ = val[E];                                             \
        const uint4 h_ = tbl[(size_t)c_ * 4 + cg];                           \
        a0 = fmaf(v_, BLO(h_.x), a0); a1 = fmaf(v_, BHI(h_.x), a1);          \
        a2 = fmaf(v_, BLO(h_.y), a2); a3 = fmaf(v_, BHI(h_.y), a3);          \
        a4 = fmaf(v_, BLO(h_.z), a4); a5 = fmaf(v_, BHI(h_.z), a5);          \
        a6 = fmaf(v_, BLO(h_.w), a6); a7 = fmaf(v_, BHI(h_.w), a7); }

    int e = start;
    for (; e + 8 <= end; e += 8) {
        STEP(e + 0) STEP(e + 1) STEP(e + 2) STEP(e + 3)
        STEP(e + 4) STEP(e + 5) STEP(e + 6) STEP(e + 7)
    }
    for (; e < end; ++e) { STEP(e) }
    #undef STEP
    #undef BLO
    #undef BHI

    float4* __restrict__ op =
        reinterpret_cast<float4*>(out) + (size_t)row * (DOUT / 4) + cg * 2;
    op[0] = make_float4(a0, a1, a2, a3);
    op[1] = make_float4(a4, a5, a6, a7);
}

// ---------------- Fallback: fused f32 (only if ws too small) ----------------
__global__ __launch_bounds__(256) void fused_kernel(
    const float* __restrict__ H, const float* __restrict__ W,
    const int* __restrict__ rowPtr, const int* __restrict__ colIdx,
    const float* __restrict__ val, float* __restrict__ out, int n)
{
    __shared__ float Wlds[DIN * DOUT];
    for (int i = threadIdx.x; i < DIN * DOUT; i += 256) Wlds[i] = W[i];
    __syncthreads();

    const int gid = blockIdx.x * 256 + threadIdx.x;
    const int row = gid >> 5;
    if (row >= n) return;
    const int c = gid & 31;

    const int start = rowPtr[row];
    const int end   = rowPtr[row + 1];
    float acc = 0.f;
    for (int e = start; e < end; ++e) {
        const int   cidx = colIdx[e];
        const float v    = val[e];
        const float* h = H + (size_t)cidx * DIN;
        float dot = 0.f;
        #pragma unroll 8
        for (int k = 0; k < DIN; ++k)
            dot = fmaf(h[k], Wlds[k * DOUT + c], dot);
        acc = fmaf(v, dot, acc);
    }
    out[(size_t)row * DOUT + c] = acc;
}

extern "C" void kernel_launch(void* const* d_in, const int* in_sizes, int n_in,
                              void* d_out, int out_size, void* d_ws, size_t ws_size,
                              hipStream_t stream)
{
    const float* H      = (const float*)d_in[0];
    const float* W      = (const float*)d_in[1];
    const int*   rowPtr = (const int*)d_in[2];
    const int*   colIdx = (const int*)d_in[3];
    const float* val    = (const float*)d_in[4];
    float*       out    = (float*)d_out;

    const int n = in_sizes[2] - 1;           // rowPtr has N+1 entries
    const size_t hw_bytes = (size_t)n * DOUT * sizeof(unsigned short);

    if (ws_size >= hw_bytes && n >= 1) {
        unsigned short* HWb = (unsigned short*)d_ws;
        gemm_hw_kernel<<<(n + GBM - 1) / GBM, 256, 0, stream>>>(H, W, HWb, n);
        const int spmm_blocks = (int)(((size_t)n * 4 + 255) / 256);
        spmm_kernel<<<spmm_blocks, 256, 0, stream>>>(HWb, rowPtr, colIdx, val, out, n);
    } else {
        const int blocks = (int)(((size_t)n * DOUT + 255) / 256);
        fused_kernel<<<blocks, 256, 0, stream>>>(H, W, rowPtr, colIdx, val, out, n);
    }
}

// Round 6
// 39.419 us; speedup vs baseline: 1.4305x; 1.3699x over previous
//
#include <hip/hip_runtime.h>

#define DIN  128
#define DOUT 32

typedef __attribute__((ext_vector_type(8))) short bf16x8;   // 8 bf16 = 4 VGPRs
typedef __attribute__((ext_vector_type(4))) float f32x4;

// f32 -> bf16 (RNE), manual
__device__ __forceinline__ unsigned int f2b(float f) {
    unsigned int u = __float_as_uint(f);
    return (u + 0x7fffu + ((u >> 16) & 1u)) >> 16;
}
// packed f32x2 -> bf16x2 (RNE), hardware
__device__ __forceinline__ unsigned int cvtpk(float lo, float hi) {
    unsigned int r;
    asm("v_cvt_pk_bf16_f32 %0, %1, %2" : "=v"(r) : "v"(lo), "v"(hi));
    return r;
}

union FragU { bf16x8 v; unsigned int u[4]; };

// ---------------- Kernel 1: HWb = bf16(H @ W) via MFMA ----------------------
// 256 thr = 4 waves, 32 rows/wave (2 row-tiles of 16), K=128 in 4 steps of 32,
// N=32 as 2 col-tiles. Per wave: 16 float4 A-loads + 64 b32 W-loads (L2-hot),
// 64 cvt_pk, 16 mfma_f32_16x16x32_bf16, 16 bf16 stores. No LDS, no barriers.
// Verified layouts (m89/m91): A row=lane&15,k=(lane>>4)*8+j; B col=lane&15,
// same k; C/D col=lane&15,row=(lane>>4)*4+reg.
__global__ __launch_bounds__(256) void gemm_mfma_kernel(
    const float* __restrict__ H, const float* __restrict__ W,
    unsigned short* __restrict__ HWb, int n)
{
    const int lane = threadIdx.x & 63;
    const int w    = threadIdx.x >> 6;
    int rb = blockIdx.x * 128 + w * 32;
    if (rb + 32 > n) rb = n - 32;      // tail overlap: identical values, benign
    const int lr = lane & 15;          // row-in-tile (A) / col-in-tile (B, C/D)
    const int kh = lane >> 4;          // 0..3: k-subchunk / C-row-quad

    // ---- B fragments from W (global, L2-resident after first blocks) ----
    bf16x8 bfrag[2][4];
    #pragma unroll
    for (int ct = 0; ct < 2; ++ct) {
        #pragma unroll
        for (int ks = 0; ks < 4; ++ks) {
            const int col = ct * 16 + lr;
            const int k0  = ks * 32 + kh * 8;
            float f[8];
            #pragma unroll
            for (int j = 0; j < 8; ++j) f[j] = W[(k0 + j) * DOUT + col];
            FragU fu;
            fu.u[0] = cvtpk(f[0], f[1]); fu.u[1] = cvtpk(f[2], f[3]);
            fu.u[2] = cvtpk(f[4], f[5]); fu.u[3] = cvtpk(f[6], f[7]);
            bfrag[ct][ks] = fu.v;
        }
    }

    f32x4 acc[2][2];
    #pragma unroll
    for (int rt = 0; rt < 2; ++rt)
        #pragma unroll
        for (int ct = 0; ct < 2; ++ct)
            acc[rt][ct] = (f32x4){0.f, 0.f, 0.f, 0.f};

    #pragma unroll
    for (int rt = 0; rt < 2; ++rt) {
        const float* __restrict__ hp = H + (size_t)(rb + rt * 16 + lr) * DIN;
        bf16x8 afrag[4];
        #pragma unroll
        for (int ks = 0; ks < 4; ++ks) {
            const int k0 = ks * 32 + kh * 8;
            const float4 lo = *reinterpret_cast<const float4*>(hp + k0);
            const float4 hi = *reinterpret_cast<const float4*>(hp + k0 + 4);
            FragU fu;
            fu.u[0] = cvtpk(lo.x, lo.y); fu.u[1] = cvtpk(lo.z, lo.w);
            fu.u[2] = cvtpk(hi.x, hi.y); fu.u[3] = cvtpk(hi.z, hi.w);
            afrag[ks] = fu.v;
        }
        #pragma unroll
        for (int ct = 0; ct < 2; ++ct)
            #pragma unroll
            for (int ks = 0; ks < 4; ++ks)
                acc[rt][ct] = __builtin_amdgcn_mfma_f32_16x16x32_bf16(
                    afrag[ks], bfrag[ct][ks], acc[rt][ct], 0, 0, 0);
    }

    // ---- store bf16: lane covers col lr of 4 rows per (rt, reg) ----
    #pragma unroll
    for (int rt = 0; rt < 2; ++rt) {
        #pragma unroll
        for (int ct = 0; ct < 2; ++ct) {
            #pragma unroll
            for (int r = 0; r < 4; ++r) {
                const int row = rb + rt * 16 + kh * 4 + r;
                const int col = ct * 16 + lr;
                HWb[(size_t)row * DOUT + col] = (unsigned short)f2b(acc[rt][ct][r]);
            }
        }
    }
}

// ---------------- Kernel 2: out = A_csr @ HWb  (bf16 gather SpMM) -----------
// UNCHANGED from round 5 (isolates the GEMM delta).
__global__ __launch_bounds__(256) void spmm_kernel(
    const unsigned short* __restrict__ HWb, const int* __restrict__ rowPtr,
    const int* __restrict__ colIdx, const float* __restrict__ val,
    float* __restrict__ out, int n)
{
    const uint4* __restrict__ tbl = reinterpret_cast<const uint4*>(HWb);
    const int gid = blockIdx.x * 256 + threadIdx.x;
    const int row = gid >> 2;
    if (row >= n) return;
    const int cg = gid & 3;

    const int start = rowPtr[row];
    const int end   = rowPtr[row + 1];
    float a0=0,a1=0,a2=0,a3=0,a4=0,a5=0,a6=0,a7=0;

    #define BLO(u) __uint_as_float((u) << 16)
    #define BHI(u) __uint_as_float((u) & 0xffff0000u)
    #define STEP(E) {                                                        \
        const int   c_ = colIdx[E];                                          \
        const float v_ = val[E];                                             \
        const uint4 h_ = tbl[(size_t)c_ * 4 + cg];                           \
        a0 = fmaf(v_, BLO(h_.x), a0); a1 = fmaf(v_, BHI(h_.x), a1);          \
        a2 = fmaf(v_, BLO(h_.y), a2); a3 = fmaf(v_, BHI(h_.y), a3);          \
        a4 = fmaf(v_, BLO(h_.z), a4); a5 = fmaf(v_, BHI(h_.z), a5);          \
        a6 = fmaf(v_, BLO(h_.w), a6); a7 = fmaf(v_, BHI(h_.w), a7); }

    int e = start;
    for (; e + 8 <= end; e += 8) {
        STEP(e + 0) STEP(e + 1) STEP(e + 2) STEP(e + 3)
        STEP(e + 4) STEP(e + 5) STEP(e + 6) STEP(e + 7)
    }
    for (; e < end; ++e) { STEP(e) }
    #undef STEP
    #undef BLO
    #undef BHI

    float4* __restrict__ op =
        reinterpret_cast<float4*>(out) + (size_t)row * (DOUT / 4) + cg * 2;
    op[0] = make_float4(a0, a1, a2, a3);
    op[1] = make_float4(a4, a5, a6, a7);
}

// ---------------- Fallback: fused f32 (ws too small or n < 32) --------------
__global__ __launch_bounds__(256) void fused_kernel(
    const float* __restrict__ H, const float* __restrict__ W,
    const int* __restrict__ rowPtr, const int* __restrict__ colIdx,
    const float* __restrict__ val, float* __restrict__ out, int n)
{
    __shared__ float Wlds[DIN * DOUT];
    for (int i = threadIdx.x; i < DIN * DOUT; i += 256) Wlds[i] = W[i];
    __syncthreads();

    const int gid = blockIdx.x * 256 + threadIdx.x;
    const int row = gid >> 5;
    if (row >= n) return;
    const int c = gid & 31;

    const int start = rowPtr[row];
    const int end   = rowPtr[row + 1];
    float acc = 0.f;
    for (int e = start; e < end; ++e) {
        const int   cidx = colIdx[e];
        const float v    = val[e];
        const float* h = H + (size_t)cidx * DIN;
        float dot = 0.f;
        #pragma unroll 8
        for (int k = 0; k < DIN; ++k)
            dot = fmaf(h[k], Wlds[k * DOUT + c], dot);
        acc = fmaf(v, dot, acc);
    }
    out[(size_t)row * DOUT + c] = acc;
}

extern "C" void kernel_launch(void* const* d_in, const int* in_sizes, int n_in,
                              void* d_out, int out_size, void* d_ws, size_t ws_size,
                              hipStream_t stream)
{
    const float* H      = (const float*)d_in[0];
    const float* W      = (const float*)d_in[1];
    const int*   rowPtr = (const int*)d_in[2];
    const int*   colIdx = (const int*)d_in[3];
    const float* val    = (const float*)d_in[4];
    float*       out    = (float*)d_out;

    const int n = in_sizes[2] - 1;           // rowPtr has N+1 entries
    const size_t hw_bytes = (size_t)n * DOUT * sizeof(unsigned short);

    if (ws_size >= hw_bytes && n >= 32) {
        unsigned short* HWb = (unsigned short*)d_ws;
        gemm_mfma_kernel<<<(n + 127) / 128, 256, 0, stream>>>(H, W, HWb, n);
        const int spmm_blocks = (int)(((size_t)n * 4 + 255) / 256);
        spmm_kernel<<<spmm_blocks, 256, 0, stream>>>(HWb, rowPtr, colIdx, val, out, n);
    } else {
        const int blocks = (int)(((size_t)n * DOUT + 255) / 256);
        fused_kernel<<<blocks, 256, 0, stream>>>(H, W, rowPtr, colIdx, val, out, n);
    }
}

// Round 7
// 38.007 us; speedup vs baseline: 1.4836x; 1.0372x over previous
//
#include <hip/hip_runtime.h>

#define DIN  128
#define DOUT 32

typedef __attribute__((ext_vector_type(8))) short bf16x8;   // 8 bf16 = 4 VGPRs
typedef __attribute__((ext_vector_type(4))) float f32x4;

// f32 -> bf16 (RNE), manual
__device__ __forceinline__ unsigned int f2b(float f) {
    unsigned int u = __float_as_uint(f);
    return (u + 0x7fffu + ((u >> 16) & 1u)) >> 16;
}
// packed f32x2 -> bf16x2 (RNE), hardware
__device__ __forceinline__ unsigned int cvtpk(float lo, float hi) {
    unsigned int r;
    asm("v_cvt_pk_bf16_f32 %0, %1, %2" : "=v"(r) : "v"(lo), "v"(hi));
    return r;
}

union FragU { bf16x8 v; unsigned int u[4]; };

// ---------------- Kernel 1: HWb = bf16(H @ W) via MFMA ----------------------
// 256 thr = 4 waves, 16 rows/wave (64 rows/block) -> 6.1 waves/SIMD for
// latency hiding. Per wave: 8 b128 A-loads + 64 b32 W-loads (L2-hot),
// 48 cvt_pk, 8 mfma_f32_16x16x32_bf16. No LDS, no barriers.
// Layouts (m89/m91-verified): A row=lane&15, k=(lane>>4)*8+j; B col=lane&15,
// same k; C/D col=lane&15, row=(lane>>4)*4+reg.
__global__ __launch_bounds__(256) void gemm_mfma_kernel(
    const float* __restrict__ H, const float* __restrict__ W,
    unsigned short* __restrict__ HWb, int n)
{
    const int lane = threadIdx.x & 63;
    const int w    = threadIdx.x >> 6;
    int rb = blockIdx.x * 64 + w * 16;
    if (rb + 16 > n) rb = n - 16;      // tail overlap: identical values, benign
    const int lr = lane & 15;
    const int kh = lane >> 4;          // 0..3

    // ---- B fragments from W ----
    bf16x8 bfrag[2][4];
    #pragma unroll
    for (int ct = 0; ct < 2; ++ct) {
        #pragma unroll
        for (int ks = 0; ks < 4; ++ks) {
            const int col = ct * 16 + lr;
            const int k0  = ks * 32 + kh * 8;
            float f[8];
            #pragma unroll
            for (int j = 0; j < 8; ++j) f[j] = W[(k0 + j) * DOUT + col];
            FragU fu;
            fu.u[0] = cvtpk(f[0], f[1]); fu.u[1] = cvtpk(f[2], f[3]);
            fu.u[2] = cvtpk(f[4], f[5]); fu.u[3] = cvtpk(f[6], f[7]);
            bfrag[ct][ks] = fu.v;
        }
    }

    // ---- A fragments: 16 rows, K=128 ----
    const float* __restrict__ hp = H + (size_t)(rb + lr) * DIN;
    bf16x8 afrag[4];
    #pragma unroll
    for (int ks = 0; ks < 4; ++ks) {
        const int k0 = ks * 32 + kh * 8;
        const float4 lo = *reinterpret_cast<const float4*>(hp + k0);
        const float4 hi = *reinterpret_cast<const float4*>(hp + k0 + 4);
        FragU fu;
        fu.u[0] = cvtpk(lo.x, lo.y); fu.u[1] = cvtpk(lo.z, lo.w);
        fu.u[2] = cvtpk(hi.x, hi.y); fu.u[3] = cvtpk(hi.z, hi.w);
        afrag[ks] = fu.v;
    }

    f32x4 acc[2] = {(f32x4){0.f,0.f,0.f,0.f}, (f32x4){0.f,0.f,0.f,0.f}};
    #pragma unroll
    for (int ct = 0; ct < 2; ++ct)
        #pragma unroll
        for (int ks = 0; ks < 4; ++ks)
            acc[ct] = __builtin_amdgcn_mfma_f32_16x16x32_bf16(
                afrag[ks], bfrag[ct][ks], acc[ct], 0, 0, 0);

    #pragma unroll
    for (int ct = 0; ct < 2; ++ct) {
        #pragma unroll
        for (int r = 0; r < 4; ++r) {
            const int row = rb + kh * 4 + r;
            const int col = ct * 16 + lr;
            HWb[(size_t)row * DOUT + col] = (unsigned short)f2b(acc[ct][r]);
        }
    }
}

// ---------------- Kernel 2: out = A_csr @ HWb  (bf16 gather SpMM) -----------
// 32 rows/block, 8 threads/row (4 cols each, uint2 = 8B gather). colIdx/val
// LDS-staged with coalesced block loads -> the random gather is the ONLY
// VMEM op in the edge loop. 12 waves/SIMD.
#define SROWS 32
__global__ __launch_bounds__(256) void spmm_kernel(
    const unsigned short* __restrict__ HWb, const int* __restrict__ rowPtr,
    const int* __restrict__ colIdx, const float* __restrict__ val,
    float* __restrict__ out, int n)
{
    __shared__ int   sPtr[SROWS + 1];
    __shared__ int   sIdx[1024];
    __shared__ float sVal[1024];

    const uint2* __restrict__ tbl = reinterpret_cast<const uint2*>(HWb);
    const int tid = threadIdx.x;
    const int r0  = blockIdx.x * SROWS;

    if (tid <= SROWS) {
        int rr = r0 + tid;
        if (rr > n) rr = n;
        sPtr[tid] = rowPtr[rr];
    }
    __syncthreads();

    const int eBase0 = sPtr[0];
    const int eEnd   = sPtr[SROWS];
    const int lrow   = tid >> 3;
    const int cg     = tid & 7;
    const int row    = r0 + lrow;
    const bool active = row < n;
    const int myS = active ? sPtr[lrow]     : 0;
    const int myE = active ? sPtr[lrow + 1] : 0;

    float a0 = 0.f, a1 = 0.f, a2 = 0.f, a3 = 0.f;

    for (int base = eBase0; base < eEnd; base += 1024) {
        const int cnt = min(1024, eEnd - base);
        if (base != eBase0) __syncthreads();   // protect LDS reuse
        for (int i = tid; i < cnt; i += 256) {
            sIdx[i] = colIdx[base + i];
            sVal[i] = val[base + i];
        }
        __syncthreads();

        const int js = max(myS, base) - base;
        const int je = min(myE, base + cnt) - base;
        #pragma unroll 8
        for (int j = js; j < je; ++j) {
            const int   c = sIdx[j];
            const float v = sVal[j];
            const uint2 g = tbl[(size_t)c * 8 + cg];
            a0 = fmaf(v, __uint_as_float(g.x << 16), a0);
            a1 = fmaf(v, __uint_as_float(g.x & 0xffff0000u), a1);
            a2 = fmaf(v, __uint_as_float(g.y << 16), a2);
            a3 = fmaf(v, __uint_as_float(g.y & 0xffff0000u), a3);
        }
    }

    if (active) {
        reinterpret_cast<float4*>(out)[(size_t)row * (DOUT / 4) + cg] =
            make_float4(a0, a1, a2, a3);
    }
}

// ---------------- Fallback: fused f32 (ws too small or n < 16) --------------
__global__ __launch_bounds__(256) void fused_kernel(
    const float* __restrict__ H, const float* __restrict__ W,
    const int* __restrict__ rowPtr, const int* __restrict__ colIdx,
    const float* __restrict__ val, float* __restrict__ out, int n)
{
    __shared__ float Wlds[DIN * DOUT];
    for (int i = threadIdx.x; i < DIN * DOUT; i += 256) Wlds[i] = W[i];
    __syncthreads();

    const int gid = blockIdx.x * 256 + threadIdx.x;
    const int row = gid >> 5;
    if (row >= n) return;
    const int c = gid & 31;

    const int start = rowPtr[row];
    const int end   = rowPtr[row + 1];
    float acc = 0.f;
    for (int e = start; e < end; ++e) {
        const int   cidx = colIdx[e];
        const float v    = val[e];
        const float* h = H + (size_t)cidx * DIN;
        float dot = 0.f;
        #pragma unroll 8
        for (int k = 0; k < DIN; ++k)
            dot = fmaf(h[k], Wlds[k * DOUT + c], dot);
        acc = fmaf(v, dot, acc);
    }
    out[(size_t)row * DOUT + c] = acc;
}

extern "C" void kernel_launch(void* const* d_in, const int* in_sizes, int n_in,
                              void* d_out, int out_size, void* d_ws, size_t ws_size,
                              hipStream_t stream)
{
    const float* H      = (const float*)d_in[0];
    const float* W      = (const float*)d_in[1];
    const int*   rowPtr = (const int*)d_in[2];
    const int*   colIdx = (const int*)d_in[3];
    const float* val    = (const float*)d_in[4];
    float*       out    = (float*)d_out;

    const int n = in_sizes[2] - 1;           // rowPtr has N+1 entries
    const size_t hw_bytes = (size_t)n * DOUT * sizeof(unsigned short);

    if (ws_size >= hw_bytes && n >= 16) {
        unsigned short* HWb = (unsigned short*)d_ws;
        gemm_mfma_kernel<<<(n + 63) / 64, 256, 0, stream>>>(H, W, HWb, n);
        const int spmm_blocks = (n + SROWS - 1) / SROWS;
        spmm_kernel<<<spmm_blocks, 256, 0, stream>>>(HWb, rowPtr, colIdx, val, out, n);
    } else {
        const int blocks = (int)(((size_t)n * DOUT + 255) / 256);
        fused_kernel<<<blocks, 256, 0, stream>>>(H, W, rowPtr, colIdx, val, out, n);
    }
}